// Round 12
// baseline (838.594 us; speedup 1.0000x reference)
//
#include <hip/hip_runtime.h>
#include <cfloat>
#include <math.h>

#define KCB 512
#define DD  64
#define TQ  3.0e-4f          // flag threshold on approx top-2 gap
#define QCAP_MAX 131072      // queue capacity (25% of N)

typedef __bf16 bf16x8 __attribute__((ext_vector_type(8)));
typedef float  f32x4  __attribute__((ext_vector_type(4)));

union U4B8 { uint4 u; bf16x8 b; };

__device__ __forceinline__ unsigned short f32_to_bf16_rne(float v) {
    unsigned int b = __float_as_uint(v);
    return (unsigned short)((b + 0x7FFFu + ((b >> 16) & 1u)) >> 16);
}

// numpy pairwise_sum (n=64) over fl(p_i^2). VALIDATED bitwise vs np (round 2).
__device__ __forceinline__ float np_sumsq64(const float* p, int stride) {
#pragma clang fp contract(off)
    float r[8];
    #pragma unroll
    for (int j = 0; j < 8; ++j) { const float v = p[j * stride]; r[j] = v * v; }
    #pragma unroll
    for (int i = 8; i < 64; i += 8) {
        #pragma unroll
        for (int j = 0; j < 8; ++j) { const float v = p[(i + j) * stride]; r[j] = r[j] + v * v; }
    }
    return ((r[0] + r[1]) + (r[2] + r[3])) + ((r[4] + r[5]) + (r[6] + r[7]));
}

// ---------------- K1: split codebook into 16x16x32-frag order + csq + zero queue
__global__ __launch_bounds__(256) void prep_kernel(const float* __restrict__ cb,
        uint4* __restrict__ wsB, float* __restrict__ csq, int* __restrict__ qcount) {
    const int u = blockIdx.x * 256 + threadIdx.x;   // [0, 8192)
    if (u == 0) *qcount = 0;
    if (u < KCB) csq[u] = np_sumsq64(cb + (size_t)u * DD, 1);

    const int lane = u & 63;
    const int f    = u >> 6;
    const int hl   = f & 1;
    const int c    = (f >> 1) & 1;
    const int t    = f >> 2;
    const int code = t * 16 + (lane & 15);
    const int dbase= c * 32 + (lane >> 4) * 8;
    const float* src = cb + (size_t)code * DD + dbase;
    const float4 p0 = *(const float4*)(src);
    const float4 p1 = *(const float4*)(src + 4);
    const float vv[8] = {p0.x, p0.y, p0.z, p0.w, p1.x, p1.y, p1.z, p1.w};
    unsigned short h[8];
    #pragma unroll
    for (int j = 0; j < 8; ++j) {
        unsigned short hb = f32_to_bf16_rne(vv[j]);
        if (hl) {
            const float hf = __uint_as_float((unsigned int)hb << 16);
            hb = f32_to_bf16_rne(vv[j] - hf);
        }
        h[j] = hb;
    }
    uint4 o;
    o.x = (unsigned)h[0] | ((unsigned)h[1] << 16);
    o.y = (unsigned)h[2] | ((unsigned)h[3] << 16);
    o.z = (unsigned)h[4] | ((unsigned)h[5] << 16);
    o.w = (unsigned)h[6] | ((unsigned)h[7] << 16);
    wsB[u] = o;
}

// ---------------- K2: round-9 structure, 8 waves/EU for MLP (the one lever)
__global__ __launch_bounds__(256, 8) void approx_kernel(const float* __restrict__ z,
        const float* __restrict__ cb, const uint4* __restrict__ wsB,
        const float* __restrict__ csq_g, unsigned* __restrict__ flags,
        float* __restrict__ out0, float* __restrict__ out1, float* __restrict__ outI) {
    __shared__ uint4 Bs[1024];      // 16 KB: one chunk = 4 code-tiles of split-B frags
    __shared__ float cqs[KCB];      // 2 KB
    __shared__ int   ridx_s[128];

    const int tid = threadIdx.x;
    const int w   = tid >> 6, l = tid & 63;
    const int col = l & 15, rq = l >> 4;
    const int r0  = blockIdx.x * 128;
    const int rowbase = r0 + w * 32;

    if (tid < 128) ((float4*)cqs)[tid] = ((const float4*)csq_g)[tid];

    // ---- A-frags for this wave's 2 row-groups: logical d = c*32 + rq*8 + j
    bf16x8 Ah[2][2], Al[2][2];
    #pragma unroll
    for (int g = 0; g < 2; ++g) {
        const int row = rowbase + g * 16 + col;
        #pragma unroll
        for (int c = 0; c < 2; ++c) {
            const float* src = z + (size_t)row * DD + c * 32 + rq * 8;
            const float4 p0 = *(const float4*)src;
            const float4 p1 = *(const float4*)(src + 4);
            const float vv[8] = {p0.x, p0.y, p0.z, p0.w, p1.x, p1.y, p1.z, p1.w};
            unsigned short hb[8], lb[8];
            #pragma unroll
            for (int j = 0; j < 8; ++j) {
                hb[j] = f32_to_bf16_rne(vv[j]);
                const float hf = __uint_as_float((unsigned)hb[j] << 16);
                lb[j] = f32_to_bf16_rne(vv[j] - hf);
            }
            U4B8 th, tl2;
            th.u.x  = (unsigned)hb[0] | ((unsigned)hb[1] << 16);
            th.u.y  = (unsigned)hb[2] | ((unsigned)hb[3] << 16);
            th.u.z  = (unsigned)hb[4] | ((unsigned)hb[5] << 16);
            th.u.w  = (unsigned)hb[6] | ((unsigned)hb[7] << 16);
            tl2.u.x = (unsigned)lb[0] | ((unsigned)lb[1] << 16);
            tl2.u.y = (unsigned)lb[2] | ((unsigned)lb[3] << 16);
            tl2.u.z = (unsigned)lb[4] | ((unsigned)lb[5] << 16);
            tl2.u.w = (unsigned)lb[6] | ((unsigned)lb[7] << 16);
            Ah[g][c] = th.b;
            Al[g][c] = tl2.b;
        }
    }

    float m1[2][4], m2[2][4];
    int   i1[2][4];
    #pragma unroll
    for (int g = 0; g < 2; ++g)
        #pragma unroll
        for (int e = 0; e < 4; ++e) { m1[g][e] = FLT_MAX; m2[g][e] = FLT_MAX; i1[g][e] = 0; }

    // chunk-order stagger: same-XCD blocks (stride-8 ids) start on different chunks
    const int start = (blockIdx.x >> 3) & 7;

    for (int cc = 0; cc < 8; ++cc) {
        const int c = (cc + start) & 7;     // chunk = tiles 4c..4c+3
        __syncthreads();                    // Bs free to overwrite (also covers cqs at cc==0)
        // ---- stage chunk c: linear LDS mirror of wsB[c*1024 .. +1024)
        {
            const uint4* gs = wsB + c * 1024 + w * 64 + l;
            #pragma unroll
            for (int i = 0; i < 4; ++i) {
                __builtin_amdgcn_global_load_lds(
                    (const __attribute__((address_space(1))) unsigned int*)(const unsigned int*)(gs + i * 256),
                    (__attribute__((address_space(3))) unsigned int*)(unsigned int*)&Bs[i * 256 + w * 64],
                    16, 0, 0);
            }
        }
        __syncthreads();                    // loads drained (compiler emits vmcnt(0) before barrier)

        #pragma unroll
        for (int tl = 0; tl < 4; ++tl) {
            const int t = c * 4 + tl;
            U4B8 Bh0, Bl0, Bh1, Bl1;
            Bh0.u = Bs[tl * 256 + l];
            Bl0.u = Bs[tl * 256 + 64 + l];
            Bh1.u = Bs[tl * 256 + 128 + l];
            Bl1.u = Bs[tl * 256 + 192 + l];
            const int   kv  = t * 16 + col;
            const float cqv = cqs[kv];

            f32x4 acc0 = {0.f, 0.f, 0.f, 0.f};
            f32x4 acc1 = {0.f, 0.f, 0.f, 0.f};
            // two independent 6-chains (g=0,1) interleaved for ILP
            acc0 = __builtin_amdgcn_mfma_f32_16x16x32_bf16(Al[0][0], Bh0.b, acc0, 0, 0, 0);
            acc1 = __builtin_amdgcn_mfma_f32_16x16x32_bf16(Al[1][0], Bh0.b, acc1, 0, 0, 0);
            acc0 = __builtin_amdgcn_mfma_f32_16x16x32_bf16(Al[0][1], Bh1.b, acc0, 0, 0, 0);
            acc1 = __builtin_amdgcn_mfma_f32_16x16x32_bf16(Al[1][1], Bh1.b, acc1, 0, 0, 0);
            acc0 = __builtin_amdgcn_mfma_f32_16x16x32_bf16(Ah[0][0], Bl0.b, acc0, 0, 0, 0);
            acc1 = __builtin_amdgcn_mfma_f32_16x16x32_bf16(Ah[1][0], Bl0.b, acc1, 0, 0, 0);
            acc0 = __builtin_amdgcn_mfma_f32_16x16x32_bf16(Ah[0][1], Bl1.b, acc0, 0, 0, 0);
            acc1 = __builtin_amdgcn_mfma_f32_16x16x32_bf16(Ah[1][1], Bl1.b, acc1, 0, 0, 0);
            acc0 = __builtin_amdgcn_mfma_f32_16x16x32_bf16(Ah[0][0], Bh0.b, acc0, 0, 0, 0);
            acc1 = __builtin_amdgcn_mfma_f32_16x16x32_bf16(Ah[1][0], Bh0.b, acc1, 0, 0, 0);
            acc0 = __builtin_amdgcn_mfma_f32_16x16x32_bf16(Ah[0][1], Bh1.b, acc0, 0, 0, 0);
            acc1 = __builtin_amdgcn_mfma_f32_16x16x32_bf16(Ah[1][1], Bh1.b, acc1, 0, 0, 0);

            #pragma unroll
            for (int e = 0; e < 4; ++e) {
                {
                    const float sc = fmaf(-2.0f, acc0[e], cqv);
                    const bool  lt = sc < m1[0][e];
                    m2[0][e] = __builtin_amdgcn_fmed3f(m2[0][e], m1[0][e], sc);  // runner-up
                    m1[0][e] = fminf(m1[0][e], sc);
                    i1[0][e] = lt ? kv : i1[0][e];
                }
                {
                    const float sc = fmaf(-2.0f, acc1[e], cqv);
                    const bool  lt = sc < m1[1][e];
                    m2[1][e] = __builtin_amdgcn_fmed3f(m2[1][e], m1[1][e], sc);
                    m1[1][e] = fminf(m1[1][e], sc);
                    i1[1][e] = lt ? kv : i1[1][e];
                }
            }
        }
    }

    // ---- reduce over the 16 code-columns (masks 1,2,4,8); lowest-index tie-break
    // (exact fp32 ties across visit order are gap==0 -> flagged -> fix resolves)
    #pragma unroll
    for (int ms = 1; ms < 16; ms <<= 1) {
        #pragma unroll
        for (int g = 0; g < 2; ++g)
            #pragma unroll
            for (int e = 0; e < 4; ++e) {
                const float om1 = __shfl_xor(m1[g][e], ms);
                const float om2 = __shfl_xor(m2[g][e], ms);
                const int   oi  = __shfl_xor(i1[g][e], ms);
                const float nm2 = fminf(fminf(m2[g][e], om2), fmaxf(m1[g][e], om1));
                const bool  tk  = (om1 < m1[g][e]) || (om1 == m1[g][e] && oi < i1[g][e]);
                m1[g][e] = tk ? om1 : m1[g][e];
                i1[g][e] = tk ? oi  : i1[g][e];
                m2[g][e] = nm2;
            }
    }
    if (col == 0) {
        #pragma unroll
        for (int g = 0; g < 2; ++g)
            #pragma unroll
            for (int e = 0; e < 4; ++e) {
                const int rl = w * 32 + g * 16 + rq * 4 + e;
                const unsigned fl = (m2[g][e] - m1[g][e] < TQ) ? 0x80000000u : 0u;
                ridx_s[rl] = (int)((unsigned)i1[g][e] | fl);
            }
    }
    // wave-local LDS exchange: writers and readers are the same wave (in-order lgkmcnt)

    // ---- per-wave flag word (bit i = row i of this wave ambiguous), no atomics
    {
        const unsigned long long bal =
            __ballot((l < 32) && (((unsigned)ridx_s[w * 32 + (l & 31)]) >> 31));
        if (l == 0) flags[blockIdx.x * 4 + w] = (unsigned)bal;
    }

    // ---- epilogue: each wave writes its own 32 rows
    #pragma unroll
    for (int it = 0; it < 8; ++it) {
        const int uu  = it * 64 + l;
        const int row = uu >> 4;            // 0..31
        const int d4  = (uu & 15) * 4;
        const int idx = ridx_s[w * 32 + row] & 0x1FF;
        const float4 qv = *(const float4*)(cb + (size_t)idx * DD + d4);
        const size_t go = (size_t)(rowbase + row) * DD + d4;
        *(float4*)(out0 + go) = qv;
        *(float4*)(out1 + go) = qv;
    }
    if (l < 32) outI[rowbase + l] = (float)(ridx_s[w * 32 + l] & 0x1FF);
}

// ---------------- K2b: compact flag words into the row queue (few atomics)
__global__ __launch_bounds__(256) void compact_kernel(const unsigned* __restrict__ flags,
        int* __restrict__ qcount, int* __restrict__ queue, int qcap, int nwords) {
    const int i = blockIdx.x * 256 + threadIdx.x;
    const int l = threadIdx.x & 63;
    unsigned m = (i < nwords) ? flags[i] : 0u;
    const int cnt = __popc(m);
    int inc = cnt;
    #pragma unroll
    for (int s = 1; s < 64; s <<= 1) {
        const int v = __shfl_up(inc, s);
        if (l >= s) inc += v;
    }
    int base = 0;
    if (l == 63) base = atomicAdd(qcount, inc);    // one atomic per wave (256 total)
    base = __shfl(base, 63);
    int off = base + inc - cnt;
    while (m) {
        const int b = __ffs(m) - 1;
        m &= m - 1;
        if (off < qcap) queue[off] = i * 32 + b;
        ++off;
    }
}

// ---------------- K3: exact numpy-replica resolve for flagged rows (validated)
#define BN 64
#define KC 128
__global__ __launch_bounds__(256) void fix_kernel(const float* __restrict__ z,
        const float* __restrict__ cb, const float* __restrict__ csq_g,
        const int* __restrict__ qcount, const int* __restrict__ queue, int qcap,
        float* __restrict__ out0, float* __restrict__ out1, float* __restrict__ outI) {
    const int cnt0 = *qcount;
    const int cnt  = cnt0 < qcap ? cnt0 : qcap;
    const int r0q  = blockIdx.x * BN;
    if (r0q >= cnt) return;

    __shared__ float xs[DD][BN];
    __shared__ float cs[DD][KC + 4];
    __shared__ float csq_s[KC];
    __shared__ float As[BN];
    __shared__ int   ridx[BN];
    __shared__ int   rows_s[BN];

    const int tid = threadIdx.x;
    const int tr  = tid >> 4;
    const int tc  = tid & 15;

    const int rsl = tid & 63;
    const int qi  = (r0q + rsl < cnt) ? (r0q + rsl) : r0q;
    const int rg  = queue[qi];
    if (tid < BN) rows_s[tid] = rg;

    {
        const int d4b = (tid >> 6) * 4;
        #pragma unroll
        for (int it = 0; it < 4; ++it) {
            const int d4 = d4b + it * 16;
            const float4 v = *(const float4*)(z + (size_t)rg * DD + d4);
            xs[d4 + 0][rsl] = v.x;
            xs[d4 + 1][rsl] = v.y;
            xs[d4 + 2][rsl] = v.z;
            xs[d4 + 3][rsl] = v.w;
        }
    }
    __syncthreads();
    if (tid < BN) As[tid] = np_sumsq64(&xs[0][tid], BN);

    float m1[4];
    int   i1[4];
    #pragma unroll
    for (int r = 0; r < 4; ++r) { m1[r] = FLT_MAX; i1[r] = KCB; }

    for (int ch = 0; ch < KCB / KC; ++ch) {
        const int kc0 = ch * KC;
        __syncthreads();
        {
            const int k   = tid & 127;
            const int d4b = (tid >> 7) * 4;
            #pragma unroll
            for (int it = 0; it < 8; ++it) {
                const int d4 = d4b + it * 8;
                const float4 v = *(const float4*)(cb + (size_t)(kc0 + k) * DD + d4);
                cs[d4 + 0][k] = v.x;
                cs[d4 + 1][k] = v.y;
                cs[d4 + 2][k] = v.z;
                cs[d4 + 3][k] = v.w;
            }
            if (tid < KC) csq_s[tid] = csq_g[kc0 + tid];
        }
        __syncthreads();

        float acc[4][8];
        #pragma unroll
        for (int r = 0; r < 4; ++r)
            #pragma unroll
            for (int j = 0; j < 8; ++j) acc[r][j] = 0.f;

        #pragma unroll 4
        for (int d = 0; d < DD; ++d) {
            const float4 xf = *(const float4*)&xs[d][tr * 4];
            const float4 c0 = *(const float4*)&cs[d][tc * 8];
            const float4 c1 = *(const float4*)&cs[d][tc * 8 + 4];
            const float xr[4] = {xf.x, xf.y, xf.z, xf.w};
            const float cc[8] = {c0.x, c0.y, c0.z, c0.w, c1.x, c1.y, c1.z, c1.w};
            #pragma unroll
            for (int r = 0; r < 4; ++r)
                #pragma unroll
                for (int j = 0; j < 8; ++j)
                    acc[r][j] = fmaf(xr[r], cc[j], acc[r][j]);
        }

        {
#pragma clang fp contract(off)
            float a4[4];
            #pragma unroll
            for (int r = 0; r < 4; ++r) a4[r] = As[tr * 4 + r];
            #pragma unroll
            for (int j = 0; j < 8; ++j) {
                const int   kg = kc0 + tc * 8 + j;
                const float cq = csq_s[tc * 8 + j];
                #pragma unroll
                for (int r = 0; r < 4; ++r) {
                    const float s = (a4[r] + cq) - 2.0f * acc[r][j];
                    if (s < m1[r]) { m1[r] = s; i1[r] = kg; }
                }
            }
        }
    }

    #pragma unroll
    for (int m = 1; m < 16; m <<= 1) {
        #pragma unroll
        for (int r = 0; r < 4; ++r) {
            const float om = __shfl_xor(m1[r], m);
            const int   oi = __shfl_xor(i1[r], m);
            if (om < m1[r] || (om == m1[r] && oi < i1[r])) { m1[r] = om; i1[r] = oi; }
        }
    }
    if (tc == 0) {
        #pragma unroll
        for (int r = 0; r < 4; ++r) ridx[tr * 4 + r] = i1[r];
    }
    __syncthreads();

    {
        #pragma unroll
        for (int it = 0; it < 4; ++it) {
            const int i   = it * 256 + tid;
            const int row = i >> 4;
            const int d4  = (i & 15) * 4;
            if (r0q + row < cnt) {
                const int grow = rows_s[row];
                const int idx  = ridx[row];
                const float4 q = *(const float4*)(cb + (size_t)idx * DD + d4);
                float4 zv;
                zv.x = xs[d4 + 0][row];
                zv.y = xs[d4 + 1][row];
                zv.z = xs[d4 + 2][row];
                zv.w = xs[d4 + 3][row];
                float4 o0;
                {
#pragma clang fp contract(off)
                    o0.x = zv.x + (q.x - zv.x);
                    o0.y = zv.y + (q.y - zv.y);
                    o0.z = zv.z + (q.z - zv.z);
                    o0.w = zv.w + (q.w - zv.w);
                }
                *(float4*)(out0 + (size_t)grow * DD + d4) = o0;
                *(float4*)(out1 + (size_t)grow * DD + d4) = q;
            }
        }
        if (tid < BN && r0q + tid < cnt) outI[rows_s[tid]] = (float)ridx[tid];
    }
}

extern "C" void kernel_launch(void* const* d_in, const int* in_sizes, int n_in,
                              void* d_out, int out_size, void* d_ws, size_t ws_size,
                              hipStream_t stream) {
    const float* z  = (const float*)d_in[0];
    const float* cb = (const float*)d_in[1];
    float* out = (float*)d_out;
    const int ND = in_sizes[0];
    const int N  = ND / DD;                  // 524288
    const int NW = N / 32;                   // flag words (one per wave)

    char*     ws     = (char*)d_ws;
    uint4*    wsB    = (uint4*)ws;                       // 131072 B
    float*    csq    = (float*)(ws + 131072);            // 2048 B
    int*      qcount = (int*)(ws + 133120);              // 16 B slot
    int*      queue  = (int*)(ws + 133136);              // 4*QCAP_MAX B
    unsigned* flags  = (unsigned*)(ws + 133136 + 4ul * QCAP_MAX);  // 4*NW B

    long qcap = QCAP_MAX;
    const size_t need = 133136 + 4ul * QCAP_MAX + 4ul * NW;
    if (ws_size < need) {
        long a = ((long)ws_size - 133136L - 4L * NW) / 4;
        qcap = a < 0 ? 0 : (a > QCAP_MAX ? QCAP_MAX : a);
        flags = (unsigned*)(ws + 133136 + 4ul * qcap);
    }

    float* out0 = out;
    float* out1 = out + (size_t)N * DD;
    float* outI = out + 2 * (size_t)N * DD;

    prep_kernel<<<32, 256, 0, stream>>>(cb, wsB, csq, qcount);
    approx_kernel<<<N / 128, 256, 0, stream>>>(z, cb, wsB, csq, flags,
                                               out0, out1, outI);
    compact_kernel<<<(NW + 255) / 256, 256, 0, stream>>>(flags, qcount, queue,
                                                         (int)qcap, NW);
    const int nq = (int)((qcap + BN - 1) / BN);
    if (nq > 0)
        fix_kernel<<<nq, 256, 0, stream>>>(z, cb, csq, qcount, queue,
                                           (int)qcap, out0, out1, outI);
}

// Round 13
// 151.006 us; speedup vs baseline: 5.5534x; 5.5534x over previous
//
#include <hip/hip_runtime.h>
#include <cfloat>
#include <math.h>

#define KCB 512
#define DD  64
#define TQA 0.0768f          // flag threshold in acc units (= 256 * 3e-4)
#define QCAP_MAX 131072      // queue capacity (25% of N)

typedef _Float16 f16x8 __attribute__((ext_vector_type(8)));
typedef float    f32x4 __attribute__((ext_vector_type(4)));

union U4H8 { uint4 u; f16x8 h; };

// numpy pairwise_sum (n=64) over fl(p_i^2). VALIDATED bitwise vs np (round 2).
__device__ __forceinline__ float np_sumsq64(const float* p, int stride) {
#pragma clang fp contract(off)
    float r[8];
    #pragma unroll
    for (int j = 0; j < 8; ++j) { const float v = p[j * stride]; r[j] = v * v; }
    #pragma unroll
    for (int i = 8; i < 64; i += 8) {
        #pragma unroll
        for (int j = 0; j < 8; ++j) { const float v = p[(i + j) * stride]; r[j] = r[j] + v * v; }
    }
    return ((r[0] + r[1]) + (r[2] + r[3])) + ((r[4] + r[5]) + (r[6] + r[7]));
}

// ---------------- K1: fp16 codebook frags (c*512, RNE) + csq + zero queue
// unit u = (t*2 + c)*64 + lane ; t = tile(16 codes), c = K-chunk(32 d)
__global__ __launch_bounds__(256) void prep_kernel(const float* __restrict__ cb,
        uint4* __restrict__ wsB, float* __restrict__ csq, int* __restrict__ qcount) {
    const int u = blockIdx.x * 256 + threadIdx.x;   // [0, 4096)
    if (u == 0) *qcount = 0;
    if (u < KCB) csq[u] = np_sumsq64(cb + (size_t)u * DD, 1);

    const int lane = u & 63;
    const int c    = (u >> 6) & 1;
    const int t    = u >> 7;
    const int code = t * 16 + (lane & 15);
    const int dbase= c * 32 + (lane >> 4) * 8;
    const float* src = cb + (size_t)code * DD + dbase;
    const float4 p0 = *(const float4*)(src);
    const float4 p1 = *(const float4*)(src + 4);
    const float vv[8] = {p0.x, p0.y, p0.z, p0.w, p1.x, p1.y, p1.z, p1.w};
    U4H8 o;
    #pragma unroll
    for (int j = 0; j < 8; ++j) o.h[j] = (_Float16)(vv[j] * 512.0f);  // exact scale, RNE cvt
    wsB[u] = o.u;
}

// ---------------- K2: fp16 single-product screening; acc = -256*score (argmax)
__global__ __launch_bounds__(256, 4) void approx_kernel(const float* __restrict__ z,
        const float* __restrict__ cb, const uint4* __restrict__ wsB,
        const float* __restrict__ csq_g, unsigned* __restrict__ flags,
        float* __restrict__ out0, float* __restrict__ out1, float* __restrict__ outI) {
    __shared__ uint4 Bs[1024];      // 16 KB: one chunk = 8 code-tiles of fp16 B frags
    __shared__ float cqs[KCB];      // 2 KB: -256 * csq
    __shared__ int   ridx_s[128];

    const int tid = threadIdx.x;
    const int w   = tid >> 6, l = tid & 63;
    const int col = l & 15, rq = l >> 4;
    const int r0  = blockIdx.x * 128;
    const int rowbase = r0 + w * 32;

    if (tid < 128) {
        float4 cv = ((const float4*)csq_g)[tid];
        cv.x *= -256.0f; cv.y *= -256.0f; cv.z *= -256.0f; cv.w *= -256.0f;
        ((float4*)cqs)[tid] = cv;
    }

    // ---- A-frags (fp16, unscaled x): logical d = c*32 + rq*8 + j (same map as B)
    f16x8 Ah[2][2];
    #pragma unroll
    for (int g = 0; g < 2; ++g) {
        const int row = rowbase + g * 16 + col;
        #pragma unroll
        for (int c = 0; c < 2; ++c) {
            const float* src = z + (size_t)row * DD + c * 32 + rq * 8;
            const float4 p0 = *(const float4*)src;
            const float4 p1 = *(const float4*)(src + 4);
            const float vv[8] = {p0.x, p0.y, p0.z, p0.w, p1.x, p1.y, p1.z, p1.w};
            f16x8 a;
            #pragma unroll
            for (int j = 0; j < 8; ++j) a[j] = (_Float16)vv[j];
            Ah[g][c] = a;
        }
    }

    // max-semantics state: M1 = best acc (= -256*best score), M2 = runner-up
    float M1[2][4], M2[2][4];
    int   i1[2][4];
    #pragma unroll
    for (int g = 0; g < 2; ++g)
        #pragma unroll
        for (int e = 0; e < 4; ++e) { M1[g][e] = -FLT_MAX; M2[g][e] = -FLT_MAX; i1[g][e] = 0; }

    // chunk-order stagger: same-XCD blocks (stride-8 ids) start on different chunks
    const int start = (blockIdx.x >> 3) & 3;

    for (int cc = 0; cc < 4; ++cc) {
        const int c = (cc + start) & 3;     // chunk = tiles 8c..8c+7
        __syncthreads();                    // Bs free to overwrite (also covers cqs at cc==0)
        {
            const uint4* gs = wsB + c * 1024 + w * 64 + l;
            #pragma unroll
            for (int i = 0; i < 4; ++i) {
                __builtin_amdgcn_global_load_lds(
                    (const __attribute__((address_space(1))) unsigned int*)(const unsigned int*)(gs + i * 256),
                    (__attribute__((address_space(3))) unsigned int*)(unsigned int*)&Bs[i * 256 + w * 64],
                    16, 0, 0);
            }
        }
        __syncthreads();                    // loads drained

        #pragma unroll
        for (int tl = 0; tl < 8; ++tl) {
            const int t = c * 8 + tl;
            U4H8 Bh0, Bh1;
            Bh0.u = Bs[tl * 128 + l];
            Bh1.u = Bs[tl * 128 + 64 + l];
            const int   kv  = t * 16 + col;
            const float cqv = cqs[kv];      // = -256*csq -> acc = -256*(csq - 2*dot)

            f32x4 acc0 = {cqv, cqv, cqv, cqv};
            f32x4 acc1 = {cqv, cqv, cqv, cqv};
            acc0 = __builtin_amdgcn_mfma_f32_16x16x32_f16(Ah[0][0], Bh0.h, acc0, 0, 0, 0);
            acc1 = __builtin_amdgcn_mfma_f32_16x16x32_f16(Ah[1][0], Bh0.h, acc1, 0, 0, 0);
            acc0 = __builtin_amdgcn_mfma_f32_16x16x32_f16(Ah[0][1], Bh1.h, acc0, 0, 0, 0);
            acc1 = __builtin_amdgcn_mfma_f32_16x16x32_f16(Ah[1][1], Bh1.h, acc1, 0, 0, 0);

            #pragma unroll
            for (int e = 0; e < 4; ++e) {
                {
                    const float a = acc0[e];
                    const bool  gt = a > M1[0][e];
                    M2[0][e] = __builtin_amdgcn_fmed3f(M2[0][e], M1[0][e], a);  // new runner-up
                    M1[0][e] = fmaxf(M1[0][e], a);
                    i1[0][e] = gt ? kv : i1[0][e];
                }
                {
                    const float a = acc1[e];
                    const bool  gt = a > M1[1][e];
                    M2[1][e] = __builtin_amdgcn_fmed3f(M2[1][e], M1[1][e], a);
                    M1[1][e] = fmaxf(M1[1][e], a);
                    i1[1][e] = gt ? kv : i1[1][e];
                }
            }
        }
    }

    // ---- reduce over the 16 code-columns; max-acc, lowest-index tie-break
    #pragma unroll
    for (int ms = 1; ms < 16; ms <<= 1) {
        #pragma unroll
        for (int g = 0; g < 2; ++g)
            #pragma unroll
            for (int e = 0; e < 4; ++e) {
                const float oM1 = __shfl_xor(M1[g][e], ms);
                const float oM2 = __shfl_xor(M2[g][e], ms);
                const int   oi  = __shfl_xor(i1[g][e], ms);
                const float nM2 = fmaxf(fmaxf(M2[g][e], oM2), fminf(M1[g][e], oM1));
                const bool  tk  = (oM1 > M1[g][e]) || (oM1 == M1[g][e] && oi < i1[g][e]);
                M1[g][e] = tk ? oM1 : M1[g][e];
                i1[g][e] = tk ? oi  : i1[g][e];
                M2[g][e] = nM2;
            }
    }
    if (col == 0) {
        #pragma unroll
        for (int g = 0; g < 2; ++g)
            #pragma unroll
            for (int e = 0; e < 4; ++e) {
                const int rl = w * 32 + g * 16 + rq * 4 + e;
                const unsigned fl = (M1[g][e] - M2[g][e] < TQA) ? 0x80000000u : 0u;
                ridx_s[rl] = (int)((unsigned)i1[g][e] | fl);
            }
    }
    // wave-local LDS exchange: writers and readers are the same wave (in-order lgkmcnt)

    // ---- per-wave flag word (no atomics)
    {
        const unsigned long long bal =
            __ballot((l < 32) && (((unsigned)ridx_s[w * 32 + (l & 31)]) >> 31));
        if (l == 0) flags[blockIdx.x * 4 + w] = (unsigned)bal;
    }

    // ---- epilogue: each wave writes its own 32 rows
    #pragma unroll
    for (int it = 0; it < 8; ++it) {
        const int uu  = it * 64 + l;
        const int row = uu >> 4;            // 0..31
        const int d4  = (uu & 15) * 4;
        const int idx = ridx_s[w * 32 + row] & 0x1FF;
        const float4 qv = *(const float4*)(cb + (size_t)idx * DD + d4);
        const size_t go = (size_t)(rowbase + row) * DD + d4;
        *(float4*)(out0 + go) = qv;
        *(float4*)(out1 + go) = qv;
    }
    if (l < 32) outI[rowbase + l] = (float)(ridx_s[w * 32 + l] & 0x1FF);
}

// ---------------- K2b: compact flag words into the row queue (few atomics)
__global__ __launch_bounds__(256) void compact_kernel(const unsigned* __restrict__ flags,
        int* __restrict__ qcount, int* __restrict__ queue, int qcap, int nwords) {
    const int i = blockIdx.x * 256 + threadIdx.x;
    const int l = threadIdx.x & 63;
    unsigned m = (i < nwords) ? flags[i] : 0u;
    const int cnt = __popc(m);
    int inc = cnt;
    #pragma unroll
    for (int s = 1; s < 64; s <<= 1) {
        const int v = __shfl_up(inc, s);
        if (l >= s) inc += v;
    }
    int base = 0;
    if (l == 63) base = atomicAdd(qcount, inc);    // one atomic per wave (256 total)
    base = __shfl(base, 63);
    int off = base + inc - cnt;
    while (m) {
        const int b = __ffs(m) - 1;
        m &= m - 1;
        if (off < qcap) queue[off] = i * 32 + b;
        ++off;
    }
}

// ---------------- K3: exact numpy-replica resolve for flagged rows (validated)
#define BN 64
#define KC 128
__global__ __launch_bounds__(256) void fix_kernel(const float* __restrict__ z,
        const float* __restrict__ cb, const float* __restrict__ csq_g,
        const int* __restrict__ qcount, const int* __restrict__ queue, int qcap,
        float* __restrict__ out0, float* __restrict__ out1, float* __restrict__ outI) {
    const int cnt0 = *qcount;
    const int cnt  = cnt0 < qcap ? cnt0 : qcap;
    const int r0q  = blockIdx.x * BN;
    if (r0q >= cnt) return;

    __shared__ float xs[DD][BN];
    __shared__ float cs[DD][KC + 4];
    __shared__ float csq_s[KC];
    __shared__ float As[BN];
    __shared__ int   ridx[BN];
    __shared__ int   rows_s[BN];

    const int tid = threadIdx.x;
    const int tr  = tid >> 4;
    const int tc  = tid & 15;

    const int rsl = tid & 63;
    const int qi  = (r0q + rsl < cnt) ? (r0q + rsl) : r0q;
    const int rg  = queue[qi];
    if (tid < BN) rows_s[tid] = rg;

    {
        const int d4b = (tid >> 6) * 4;
        #pragma unroll
        for (int it = 0; it < 4; ++it) {
            const int d4 = d4b + it * 16;
            const float4 v = *(const float4*)(z + (size_t)rg * DD + d4);
            xs[d4 + 0][rsl] = v.x;
            xs[d4 + 1][rsl] = v.y;
            xs[d4 + 2][rsl] = v.z;
            xs[d4 + 3][rsl] = v.w;
        }
    }
    __syncthreads();
    if (tid < BN) As[tid] = np_sumsq64(&xs[0][tid], BN);

    float m1[4];
    int   i1[4];
    #pragma unroll
    for (int r = 0; r < 4; ++r) { m1[r] = FLT_MAX; i1[r] = KCB; }

    for (int ch = 0; ch < KCB / KC; ++ch) {
        const int kc0 = ch * KC;
        __syncthreads();
        {
            const int k   = tid & 127;
            const int d4b = (tid >> 7) * 4;
            #pragma unroll
            for (int it = 0; it < 8; ++it) {
                const int d4 = d4b + it * 8;
                const float4 v = *(const float4*)(cb + (size_t)(kc0 + k) * DD + d4);
                cs[d4 + 0][k] = v.x;
                cs[d4 + 1][k] = v.y;
                cs[d4 + 2][k] = v.z;
                cs[d4 + 3][k] = v.w;
            }
            if (tid < KC) csq_s[tid] = csq_g[kc0 + tid];
        }
        __syncthreads();

        float acc[4][8];
        #pragma unroll
        for (int r = 0; r < 4; ++r)
            #pragma unroll
            for (int j = 0; j < 8; ++j) acc[r][j] = 0.f;

        #pragma unroll 4
        for (int d = 0; d < DD; ++d) {
            const float4 xf = *(const float4*)&xs[d][tr * 4];
            const float4 c0 = *(const float4*)&cs[d][tc * 8];
            const float4 c1 = *(const float4*)&cs[d][tc * 8 + 4];
            const float xr[4] = {xf.x, xf.y, xf.z, xf.w};
            const float cc[8] = {c0.x, c0.y, c0.z, c0.w, c1.x, c1.y, c1.z, c1.w};
            #pragma unroll
            for (int r = 0; r < 4; ++r)
                #pragma unroll
                for (int j = 0; j < 8; ++j)
                    acc[r][j] = fmaf(xr[r], cc[j], acc[r][j]);
        }

        {
#pragma clang fp contract(off)
            float a4[4];
            #pragma unroll
            for (int r = 0; r < 4; ++r) a4[r] = As[tr * 4 + r];
            #pragma unroll
            for (int j = 0; j < 8; ++j) {
                const int   kg = kc0 + tc * 8 + j;
                const float cq = csq_s[tc * 8 + j];
                #pragma unroll
                for (int r = 0; r < 4; ++r) {
                    const float s = (a4[r] + cq) - 2.0f * acc[r][j];
                    if (s < m1[r]) { m1[r] = s; i1[r] = kg; }
                }
            }
        }
    }

    #pragma unroll
    for (int m = 1; m < 16; m <<= 1) {
        #pragma unroll
        for (int r = 0; r < 4; ++r) {
            const float om = __shfl_xor(m1[r], m);
            const int   oi = __shfl_xor(i1[r], m);
            if (om < m1[r] || (om == m1[r] && oi < i1[r])) { m1[r] = om; i1[r] = oi; }
        }
    }
    if (tc == 0) {
        #pragma unroll
        for (int r = 0; r < 4; ++r) ridx[tr * 4 + r] = i1[r];
    }
    __syncthreads();

    {
        #pragma unroll
        for (int it = 0; it < 4; ++it) {
            const int i   = it * 256 + tid;
            const int row = i >> 4;
            const int d4  = (i & 15) * 4;
            if (r0q + row < cnt) {
                const int grow = rows_s[row];
                const int idx  = ridx[row];
                const float4 q = *(const float4*)(cb + (size_t)idx * DD + d4);
                float4 zv;
                zv.x = xs[d4 + 0][row];
                zv.y = xs[d4 + 1][row];
                zv.z = xs[d4 + 2][row];
                zv.w = xs[d4 + 3][row];
                float4 o0;
                {
#pragma clang fp contract(off)
                    o0.x = zv.x + (q.x - zv.x);
                    o0.y = zv.y + (q.y - zv.y);
                    o0.z = zv.z + (q.z - zv.z);
                    o0.w = zv.w + (q.w - zv.w);
                }
                *(float4*)(out0 + (size_t)grow * DD + d4) = o0;
                *(float4*)(out1 + (size_t)grow * DD + d4) = q;
            }
        }
        if (tid < BN && r0q + tid < cnt) outI[rows_s[tid]] = (float)ridx[tid];
    }
}

extern "C" void kernel_launch(void* const* d_in, const int* in_sizes, int n_in,
                              void* d_out, int out_size, void* d_ws, size_t ws_size,
                              hipStream_t stream) {
    const float* z  = (const float*)d_in[0];
    const float* cb = (const float*)d_in[1];
    float* out = (float*)d_out;
    const int ND = in_sizes[0];
    const int N  = ND / DD;                  // 524288
    const int NW = N / 32;                   // flag words (one per wave)

    char*     ws     = (char*)d_ws;
    uint4*    wsB    = (uint4*)ws;                       // 65536 B (fp16 frags)
    float*    csq    = (float*)(ws + 65536);             // 2048 B
    int*      qcount = (int*)(ws + 67584);               // 16 B slot
    int*      queue  = (int*)(ws + 67600);               // 4*QCAP_MAX B
    unsigned* flags  = (unsigned*)(ws + 67600 + 4ul * QCAP_MAX);  // 4*NW B

    long qcap = QCAP_MAX;
    const size_t need = 67600 + 4ul * QCAP_MAX + 4ul * NW;
    if (ws_size < need) {
        long a = ((long)ws_size - 67600L - 4L * NW) / 4;
        qcap = a < 0 ? 0 : (a > QCAP_MAX ? QCAP_MAX : a);
        flags = (unsigned*)(ws + 67600 + 4ul * qcap);
    }

    float* out0 = out;
    float* out1 = out + (size_t)N * DD;
    float* outI = out + 2 * (size_t)N * DD;

    prep_kernel<<<16, 256, 0, stream>>>(cb, wsB, csq, qcount);
    approx_kernel<<<N / 128, 256, 0, stream>>>(z, cb, wsB, csq, flags,
                                               out0, out1, outI);
    compact_kernel<<<(NW + 255) / 256, 256, 0, stream>>>(flags, qcount, queue,
                                                         (int)qcap, NW);
    const int nq = (int)((qcap + BN - 1) / BN);
    if (nq > 0)
        fix_kernel<<<nq, 256, 0, stream>>>(z, cb, csq, qcount, queue,
                                           (int)qcap, out0, out1, outI);
}